// Round 16
// baseline (50.071 us; speedup 1.0000x reference)
//
#include <hip/hip_runtime.h>
#include <hip/hip_bf16.h>
#include <stdint.h>

#define BB 8
#define TT 2048
#define CC 768
#define NTPB 72   // flash block-tasks per batch: sum_{g=0..15} ceil((g+1)/2)

typedef __bf16 bf16x8 __attribute__((ext_vector_type(8)));
typedef float f32x4 __attribute__((ext_vector_type(4)));
typedef float f32x16 __attribute__((ext_vector_type(16)));

__device__ inline __bf16 f2b(float f) {
    __hip_bfloat16 h = __float2bfloat16(f);
    return __builtin_bit_cast(__bf16, h);
}
__device__ inline ushort f2bits(float f) {
    __hip_bfloat16 h = __float2bfloat16(f);
    return __builtin_bit_cast(ushort, h);
}
__device__ inline float bits2f(ushort u) {
    return __builtin_bit_cast(float, ((uint32_t)u) << 16);
}
__device__ inline uint32_t cvtpk(float lo, float hi) {
    uint32_t r;
    asm("v_cvt_pk_bf16_f32 %0, %1, %2" : "=v"(r) : "v"(lo), "v"(hi));
    return r;
}
__device__ inline void pswap(uint32_t& a, uint32_t& b) {
    asm volatile("v_permlane32_swap_b32 %0, %1" : "+v"(a), "+v"(b));
}

#define GLL16(gp, lp)                                                          \
    __builtin_amdgcn_global_load_lds(                                          \
        (const __attribute__((address_space(1))) unsigned int*)(gp),           \
        (__attribute__((address_space(3))) unsigned int*)(lp), 16, 0, 0)

// ---------------- Kernel 0: W -> fragment-major bf16 WtF -----------------
__launch_bounds__(256)
__global__ void wt_kernel(const float* __restrict__ Wk, const float* __restrict__ Wq,
                          const float* __restrict__ Wv, ushort* __restrict__ WtF) {
    __shared__ float tile[64][65];
    int m  = blockIdx.x / 12;
    int c0 = (blockIdx.x % 12) * 64;
    const float* W = (m == 0) ? Wq : ((m == 1) ? Wk : Wv);
    int tid = threadIdx.x;
#pragma unroll
    for (int i = 0; i < 4; i++) {
        int r   = (tid >> 4) + i * 16;
        int col = (tid & 15) * 4;
        float4 v = *(const float4*)&W[(size_t)(c0 + r) * 64 + col];
        tile[r][col] = v.x; tile[r][col + 1] = v.y;
        tile[r][col + 2] = v.z; tile[r][col + 3] = v.w;
    }
    __syncthreads();
    int j  = tid >> 2;
    int cc = (tid & 3) * 16;
    ushort tmp[16];
#pragma unroll
    for (int e = 0; e < 16; e++) tmp[e] = f2bits(tile[cc + e][j]);
    int c  = m * 64 + j;
    int kb = c0 + cc;
    int kc = kb >> 5;
    int h4 = (kb >> 3) & 3;
    ushort* dst = &WtF[((size_t)kc * 192 + c) * 32 + h4 * 8];
    *(uint4*)(dst)     = *(uint4*)&tmp[0];
    *(uint4*)(dst + 8) = *(uint4*)&tmp[8];
}

// ---------------- Kernel 1: QKV GEMM v3 — asymmetric-depth pipeline ------
// Block: 32 rows x 192 cols, 4 waves; 12 phases x 2 BK=32 tiles.
// A[4] buffers (16KB, HBM, lead 2 phases) + B[3] (36KB, L2, lead 1 phase)
// = 52KB -> 3 blocks/CU (12 waves/CU). Steady vmcnt(2): issue order per
// phase {B(2p+2)x3, B(2p+3)x3, A(2p+4), A(2p+5)} keeps the next A-pair
// youngest. Prologue ordered A0,A1,B0,B1,A2,A3 for the same reason.
__launch_bounds__(256, 3)
__global__ void qkv_kernel(const float* __restrict__ x, const ushort* __restrict__ WtF,
                           ushort* __restrict__ qws, ushort* __restrict__ kws,
                           ushort* __restrict__ vws) {
    __shared__ float  xsA[4][32 * 32];   // 4 x 4 KB
    __shared__ ushort xsB[3][6144];      // 3 x 12 KB

    int tid  = threadIdx.x;
    int wid  = tid >> 6;
    int lane = tid & 63;
    int l15  = lane & 15;
    int hi4  = lane >> 4;
    int row0 = blockIdx.x * 32;

    int rA  = tid >> 3;
    int gcA = (tid & 7) ^ (rA & 7);
    const float* gpA = x + (size_t)(row0 + rA) * CC + gcA * 4;

    int PB0 = tid, PB1 = tid + 256, PB2 = tid + 512;
    int LB0 = PB0 ^ ((PB0 >> 3) & 3);
    int LB1 = PB1 ^ ((PB1 >> 3) & 3);
    int LB2 = PB2 ^ ((PB2 >> 3) & 3);

    int PrB[3];
#pragma unroll
    for (int nt = 0; nt < 3; nt++) {
        int Lr = (wid * 48 + nt * 16 + l15) * 4 + hi4;
        PrB[nt] = Lr ^ ((Lr >> 3) & 3);
    }

    f32x4 acc[2][3];
#pragma unroll
    for (int mm = 0; mm < 2; mm++)
#pragma unroll
        for (int nt = 0; nt < 3; nt++) acc[mm][nt] = (f32x4){0.f, 0.f, 0.f, 0.f};

    auto stageA = [&](int t) {
        GLL16(gpA + t * 32, &xsA[t & 3][(size_t)tid * 4]);
    };
    auto stageB = [&](int t) {
        int buf = t % 3;
        const ushort* bsrc = WtF + (size_t)t * 6144;
        GLL16(bsrc + LB0 * 8, &xsB[buf][PB0 * 8]);
        GLL16(bsrc + LB1 * 8, &xsB[buf][PB1 * 8]);
        GLL16(bsrc + LB2 * 8, &xsB[buf][PB2 * 8]);
    };

    // prologue: needed-first, not-needed (A2,A3) youngest
    stageA(0); stageA(1);
    stageB(0); stageB(1);
    stageA(2); stageA(3);

#pragma unroll
    for (int p = 0; p < 12; p++) {
        if (p < 11) asm volatile("s_waitcnt vmcnt(2)" ::: "memory");
        else        asm volatile("s_waitcnt vmcnt(0)" ::: "memory");
        __builtin_amdgcn_s_barrier();
        __builtin_amdgcn_sched_barrier(0);

#pragma unroll
        for (int u = 0; u < 2; u++) {
            int t    = 2 * p + u;
            int bufA = t & 3;
            int bufB = t % 3;
            bf16x8 af[2];
#pragma unroll
            for (int mm = 0; mm < 2; mm++) {
                int row = mm * 16 + l15;
                const float* base = &xsA[bufA][row * 32];
                float4 fa = *(const float4*)(base + (((2 * hi4)     ^ (row & 7)) * 4));
                float4 fb = *(const float4*)(base + (((2 * hi4 + 1) ^ (row & 7)) * 4));
                uint32_t w0 = cvtpk(fa.x, fa.y), w1 = cvtpk(fa.z, fa.w);
                uint32_t w2 = cvtpk(fb.x, fb.y), w3 = cvtpk(fb.z, fb.w);
                uint4 u4 = {w0, w1, w2, w3};
                af[mm] = __builtin_bit_cast(bf16x8, u4);
            }
#pragma unroll
            for (int nt = 0; nt < 3; nt++) {
                bf16x8 b = __builtin_bit_cast(bf16x8, *(const uint4*)&xsB[bufB][PrB[nt] * 8]);
                acc[0][nt] = __builtin_amdgcn_mfma_f32_16x16x32_bf16(af[0], b, acc[0][nt], 0, 0, 0);
                acc[1][nt] = __builtin_amdgcn_mfma_f32_16x16x32_bf16(af[1], b, acc[1][nt], 0, 0, 0);
            }
        }
        __builtin_amdgcn_s_barrier();      // reads done; freed bufs restageable
        if (p < 11) { stageB(2 * p + 2); stageB(2 * p + 3); }
        if (p < 10) { stageA(2 * p + 4); stageA(2 * p + 5); }
    }

    const float qscale = 0.125f * 1.4426950408889634f;   // exp2 domain
    int bidx = row0 >> 11;
#pragma unroll
    for (int mm = 0; mm < 2; mm++) {
        int r0 = row0 + mm * 16 + 4 * hi4;
        int t0 = r0 & 2047;
#pragma unroll
        for (int nt = 0; nt < 3; nt++) {
            int c = wid * 48 + nt * 16 + l15;
            int m = c >> 6;
            int j = c & 63;
            if (m == 0) {
#pragma unroll
                for (int r = 0; r < 4; r++)
                    qws[(size_t)(r0 + r) * 64 + j] = f2bits(acc[mm][nt][r] * qscale);
            } else if (m == 1) {
#pragma unroll
                for (int r = 0; r < 4; r++)
                    kws[(size_t)(r0 + r) * 64 + j] = f2bits(acc[mm][nt][r]);
            } else {
                ushort4 pk;
                pk.x = f2bits(acc[mm][nt][0]);
                pk.y = f2bits(acc[mm][nt][1]);
                pk.z = f2bits(acc[mm][nt][2]);
                pk.w = f2bits(acc[mm][nt][3]);
                *(ushort4*)&vws[((size_t)bidx * 64 + j) * TT + t0] = pk;
            }
        }
    }
}

// ---------------- Kernel 2: flash, XCD-aligned batches (R15, unchanged) --
__launch_bounds__(256, 3)
__global__ void flash_kernel(const ushort* __restrict__ qg, const ushort* __restrict__ kg,
                             const ushort* __restrict__ vtg, float* __restrict__ out,
                             ushort* __restrict__ pO, float* __restrict__ pM,
                             float* __restrict__ pL) {
    __shared__ ushort Ks[3][64 * 64];
    __shared__ ushort Vs[3][64 * 64];

    int tid  = threadIdx.x;
    int wid  = tid >> 6;
    int lane = tid & 63;
    int l31  = lane & 31;
    int hi   = lane >> 5;

    int b  = blockIdx.x & 7;            // XCD-aligned batch
    int tp = blockIdx.x >> 3;
    int g  = 0;
    while (tp >= ((g + 2) * (g + 2)) >> 2) g++;
    int seg   = tp - (((g + 1) * (g + 1)) >> 2);
    int nseg  = (g + 2) >> 1;
    int Qb    = g * 128;
    int Q0w   = Qb + wid * 32;
    int s_beg = seg * 256;
    int s_end = (s_beg + 256 < Qb + 128) ? s_beg + 256 : Qb + 128;
    int nt    = (s_end - s_beg) >> 6;

    int rS  = tid >> 3;
    int gcS = (tid & 7) ^ (rS & 7);
    const ushort* kS = kg  + ((size_t)b * TT + rS) * 64 + gcS * 8;
    const ushort* vS = vtg + ((size_t)b * 64 + rS) * TT + gcS * 8;

    auto stage = [&](int tt) {
        int buf = tt % 3;
        int ss  = s_beg + tt * 64;
        const ushort* kA = kS + (size_t)ss * 64;
        const ushort* vA = vS + ss;
        GLL16(kA,            &Ks[buf][tid * 8]);
        GLL16(kA + 32 * 64,  &Ks[buf][(tid + 256) * 8]);
        GLL16(vA,            &Vs[buf][tid * 8]);
        GLL16(vA + 32 * TT,  &Vs[buf][(tid + 256) * 8]);
    };

    const ushort* qp = qg + ((size_t)b * TT + Q0w + l31) * 64 + hi * 8;
    bf16x8 qf[4];
#pragma unroll
    for (int c = 0; c < 4; c++)
        qf[c] = __builtin_bit_cast(bf16x8, *(const uint4*)(qp + c * 16));

    f32x16 o0 = (f32x16)(0.f), o1 = (f32x16)(0.f);
    float m  = -INFINITY;
    float lp = 0.f;

    stage(0);
    if (nt > 1) stage(1);

    for (int t = 0; t < nt; t++) {
        if (t < nt - 1) asm volatile("s_waitcnt vmcnt(4)" ::: "memory");
        else            asm volatile("s_waitcnt vmcnt(0)" ::: "memory");
        __builtin_amdgcn_s_barrier();
        __builtin_amdgcn_sched_barrier(0);
        if (t + 2 < nt) stage(t + 2);

        int s0 = s_beg + t * 64;
        if (s0 < Q0w + 32) {
            int buf = t % 3;
            bf16x8 kf[2][4];
#pragma unroll
            for (int tt = 0; tt < 2; tt++) {
                int rk = tt * 32 + l31;
                const ushort* base = &Ks[buf][rk * 64];
                int sw = rk & 7;
#pragma unroll
                for (int c = 0; c < 4; c++)
                    kf[tt][c] = __builtin_bit_cast(bf16x8,
                        *(const uint4*)(base + (((c * 2 + hi) ^ sw) * 8)));
            }

            f32x16 st0 = (f32x16)(0.f), st1 = (f32x16)(0.f);
            __builtin_amdgcn_s_setprio(1);
#pragma unroll
            for (int c = 0; c < 4; c++)
                st0 = __builtin_amdgcn_mfma_f32_32x32x16_bf16(kf[0][c], qf[c], st0, 0, 0, 0);
#pragma unroll
            for (int c = 0; c < 4; c++)
                st1 = __builtin_amdgcn_mfma_f32_32x32x16_bf16(kf[1][c], qf[c], st1, 0, 0, 0);
            __builtin_amdgcn_s_setprio(0);

            if (s0 + 63 > Q0w) {
                int th0 = Q0w + l31 - s0 - 4 * hi;
                int th1 = th0 - 32;
#pragma unroll
                for (int r = 0; r < 16; r++) {
                    int kvl = (r & 3) + 8 * (r >> 2);
                    if (kvl > th0) st0[r] = -INFINITY;
                    if (kvl > th1) st1[r] = -INFINITY;
                }
            }

            float a[16];
#pragma unroll
            for (int r = 0; r < 16; r++) a[r] = fmaxf(st0[r], st1[r]);
#pragma unroll
            for (int off = 8; off > 0; off >>= 1)
#pragma unroll
                for (int i = 0; i < 8; i++)
                    if (i < off) a[i] = fmaxf(a[i], a[i + off]);
            float pmax = fmaxf(a[0], __shfl_xor(a[0], 32));
            if (__any(pmax > m + 11.54f)) {
                float mn = fmaxf(m, pmax);
                float al = exp2f(m - mn);
                lp *= al;
#pragma unroll
                for (int r = 0; r < 16; r++) { o0[r] *= al; o1[r] *= al; }
                m = mn;
            }
#pragma unroll
            for (int r = 0; r < 16; r++) {
                st0[r] = exp2f(st0[r] - m);
                st1[r] = exp2f(st1[r] - m);
            }
            float s[16];
#pragma unroll
            for (int r = 0; r < 16; r++) s[r] = st0[r] + st1[r];
#pragma unroll
            for (int off = 8; off > 0; off >>= 1)
#pragma unroll
                for (int i = 0; i < 8; i++)
                    if (i < off) s[i] += s[i + off];
            lp += s[0];

            bf16x8 pf[4];
            {
                uint32_t w0, w1, w2, w3;
                w0 = cvtpk(st0[0], st0[1]);  w1 = cvtpk(st0[2], st0[3]);
                w2 = cvtpk(st0[4], st0[5]);  w3 = cvtpk(st0[6], st0[7]);
                pswap(w0, w2); pswap(w1, w3);
                uint4 u0 = {w0, w1, w2, w3}; pf[0] = __builtin_bit_cast(bf16x8, u0);
                w0 = cvtpk(st0[8], st0[9]);  w1 = cvtpk(st0[10], st0[11]);
                w2 = cvtpk(st0[12], st0[13]); w3 = cvtpk(st0[14], st0[15]);
                pswap(w0, w2); pswap(w1, w3);
                uint4 u1 = {w0, w1, w2, w3}; pf[1] = __builtin_bit_cast(bf16x8, u1);
                w0 = cvtpk(st1[0], st1[1]);  w1 = cvtpk(st1[2], st1[3]);
                w2 = cvtpk(st1[4], st1[5]);  w3 = cvtpk(st1[6], st1[7]);
                pswap(w0, w2); pswap(w1, w3);
                uint4 u2 = {w0, w1, w2, w3}; pf[2] = __builtin_bit_cast(bf16x8, u2);
                w0 = cvtpk(st1[8], st1[9]);  w1 = cvtpk(st1[10], st1[11]);
                w2 = cvtpk(st1[12], st1[13]); w3 = cvtpk(st1[14], st1[15]);
                pswap(w0, w2); pswap(w1, w3);
                uint4 u3 = {w0, w1, w2, w3}; pf[3] = __builtin_bit_cast(bf16x8, u3);
            }

            bf16x8 vf[2][4];
#pragma unroll
            for (int ht = 0; ht < 2; ht++) {
                int rv = ht * 32 + l31;
                const ushort* base = &Vs[buf][rv * 64];
                int sw = rv & 7;
#pragma unroll
                for (int c = 0; c < 4; c++)
                    vf[ht][c] = __builtin_bit_cast(bf16x8,
                        *(const uint4*)(base + (((c * 2 + hi) ^ sw) * 8)));
            }

            __builtin_amdgcn_s_setprio(1);
#pragma unroll
            for (int c = 0; c < 4; c++)
                o0 = __builtin_amdgcn_mfma_f32_32x32x16_bf16(vf[0][c], pf[c], o0, 0, 0, 0);
#pragma unroll
            for (int c = 0; c < 4; c++)
                o1 = __builtin_amdgcn_mfma_f32_32x32x16_bf16(vf[1][c], pf[c], o1, 0, 0, 0);
            __builtin_amdgcn_s_setprio(0);
        }
    }

    float lsum = lp + __shfl_xor(lp, 32);

    if (nseg == 1) {
        float inv = 1.f / lsum;
        float* ob = out + ((size_t)b * TT + Q0w + l31) * 64;
#pragma unroll
        for (int gg = 0; gg < 4; gg++) {
            float4 v0 = {o0[4*gg] * inv, o0[4*gg+1] * inv, o0[4*gg+2] * inv, o0[4*gg+3] * inv};
            *(float4*)(ob + 8 * gg + 4 * hi) = v0;
            float4 v1 = {o1[4*gg] * inv, o1[4*gg+1] * inv, o1[4*gg+2] * inv, o1[4*gg+3] * inv};
            *(float4*)(ob + 32 + 8 * gg + 4 * hi) = v1;
        }
    } else {
        int tb = b * NTPB + tp;
        ushort* pb = pO + (size_t)tb * 8192 + (size_t)(wid * 32 + l31) * 64;
#pragma unroll
        for (int gg = 0; gg < 4; gg++) {
            ushort4 v0 = {f2bits(o0[4*gg]), f2bits(o0[4*gg+1]),
                          f2bits(o0[4*gg+2]), f2bits(o0[4*gg+3])};
            *(ushort4*)(pb + 8 * gg + 4 * hi) = v0;
            ushort4 v1 = {f2bits(o1[4*gg]), f2bits(o1[4*gg+1]),
                          f2bits(o1[4*gg+2]), f2bits(o1[4*gg+3])};
            *(ushort4*)(pb + 32 + 8 * gg + 4 * hi) = v1;
        }
        if (hi == 0) {
            pM[(size_t)tb * 128 + wid * 32 + l31] = m;
            pL[(size_t)tb * 128 + wid * 32 + l31] = lsum;
        }
    }
}

// ---------------- Kernel 3: merge bf16 partials (g >= 2) -----------------
__launch_bounds__(256)
__global__ void merge_kernel(const ushort* __restrict__ pO, const float* __restrict__ pM,
                             const float* __restrict__ pL, float* __restrict__ out) {
    int b    = blockIdx.x / 14;
    int g    = 2 + (blockIdx.x % 14);
    int nseg = (g + 2) >> 1;
    int tbase = b * NTPB + (((g + 1) * (g + 1)) >> 2);

    int row = threadIdx.x >> 1;
    int hh  = (threadIdx.x & 1) * 32;

    float mstar = -INFINITY;
    for (int s = 0; s < nseg; s++)
        mstar = fmaxf(mstar, pM[(size_t)(tbase + s) * 128 + row]);

    float oa[32];
#pragma unroll
    for (int i = 0; i < 32; i++) oa[i] = 0.f;
    float la = 0.f;
    for (int s = 0; s < nseg; s++) {
        float w = exp2f(pM[(size_t)(tbase + s) * 128 + row] - mstar);
        la += w * pL[(size_t)(tbase + s) * 128 + row];
        const ushort* pp = pO + (size_t)(tbase + s) * 8192 + (size_t)row * 64 + hh;
        uint4 u0 = *(const uint4*)(pp);
        uint4 u1 = *(const uint4*)(pp + 8);
        uint4 u2 = *(const uint4*)(pp + 16);
        uint4 u3 = *(const uint4*)(pp + 24);
        const uint4 uu[4] = {u0, u1, u2, u3};
#pragma unroll
        for (int q = 0; q < 4; q++) {
#pragma unroll
            for (int e = 0; e < 4; e++) {
                uint32_t wdw = ((const uint32_t*)&uu[q])[e];
                oa[q*8 + e*2]     += w * bits2f((ushort)(wdw & 0xffff));
                oa[q*8 + e*2 + 1] += w * bits2f((ushort)(wdw >> 16));
            }
        }
    }
    float inv = 1.f / la;
    float* ob = out + ((size_t)b * TT + g * 128 + row) * 64 + hh;
#pragma unroll
    for (int i = 0; i < 8; i++) {
        float4 v = {oa[i*4] * inv, oa[i*4+1] * inv, oa[i*4+2] * inv, oa[i*4+3] * inv};
        *(float4*)(ob + i * 4) = v;
    }
}

// ---------------- launch --------------------------------------------------
extern "C" void kernel_launch(void* const* d_in, const int* in_sizes, int n_in,
                              void* d_out, int out_size, void* d_ws, size_t ws_size,
                              hipStream_t stream) {
    const float* x  = (const float*)d_in[0];
    const float* Wk = (const float*)d_in[1];
    const float* Wq = (const float*)d_in[2];
    const float* Wv = (const float*)d_in[3];
    float* out = (float*)d_out;

    char* ws = (char*)d_ws;
    ushort* WtF = (ushort*)(ws);                 // 288 KB (fragment-major)
    ushort* qws = (ushort*)(ws + 0x50000);       // 2 MB
    ushort* kws = (ushort*)(ws + 0x250000);      // 2 MB
    ushort* vws = (ushort*)(ws + 0x450000);      // 2 MB  [b][h][t]
    ushort* pO  = (ushort*)(ws + 0x650000);      // 9.4 MB (bf16 partials)
    float*  pM  = (float*)(ws + 0x1050000);      // 288 KB
    float*  pL  = (float*)(ws + 0x1098000);      // 288 KB

    wt_kernel<<<36, 256, 0, stream>>>(Wk, Wq, Wv, WtF);
    qkv_kernel<<<(BB * TT) / 32, 256, 0, stream>>>(x, WtF, qws, kws, vws);
    flash_kernel<<<BB * NTPB, 256, 0, stream>>>(qws, kws, vws, out, pO, pM, pL);
    merge_kernel<<<BB * 14, 256, 0, stream>>>(pO, pM, pL, out);
}

// Round 17
// 45.854 us; speedup vs baseline: 1.0920x; 1.0920x over previous
//
#include <hip/hip_runtime.h>
#include <hip/hip_bf16.h>
#include <stdint.h>

#define BB 8
#define TT 2048
#define CC 768
#define NTPB 72   // flash block-tasks per batch: sum_{g=0..15} ceil((g+1)/2)

typedef __bf16 bf16x8 __attribute__((ext_vector_type(8)));
typedef float f32x4 __attribute__((ext_vector_type(4)));
typedef float f32x16 __attribute__((ext_vector_type(16)));

__device__ inline __bf16 f2b(float f) {
    __hip_bfloat16 h = __float2bfloat16(f);
    return __builtin_bit_cast(__bf16, h);
}
__device__ inline ushort f2bits(float f) {
    __hip_bfloat16 h = __float2bfloat16(f);
    return __builtin_bit_cast(ushort, h);
}
__device__ inline float bits2f(ushort u) {
    return __builtin_bit_cast(float, ((uint32_t)u) << 16);
}
__device__ inline uint32_t cvtpk(float lo, float hi) {
    uint32_t r;
    asm("v_cvt_pk_bf16_f32 %0, %1, %2" : "=v"(r) : "v"(lo), "v"(hi));
    return r;
}
__device__ inline void pswap(uint32_t& a, uint32_t& b) {
    asm volatile("v_permlane32_swap_b32 %0, %1" : "+v"(a), "+v"(b));
}

#define GLL16(gp, lp)                                                          \
    __builtin_amdgcn_global_load_lds(                                          \
        (const __attribute__((address_space(1))) unsigned int*)(gp),           \
        (__attribute__((address_space(3))) unsigned int*)(lp), 16, 0, 0)

// ---------------- Kernel 0: W -> fragment-major bf16 WtF (72 blocks) -----
// Block = (m, 32-k tile). Each thread: 2 float4 loads, 8 LDS reads, 1 uint4
// store. h4 = sub because c0 is 32-aligned.
__launch_bounds__(256)
__global__ void wt_kernel(const float* __restrict__ Wk, const float* __restrict__ Wq,
                          const float* __restrict__ Wv, ushort* __restrict__ WtF) {
    __shared__ float tile[32][65];
    int m  = blockIdx.x / 24;
    int c0 = (blockIdx.x % 24) * 32;     // k-base, 32-aligned
    const float* W = (m == 0) ? Wq : ((m == 1) ? Wk : Wv);
    int tid = threadIdx.x;
    {
        int r   = tid >> 3;              // 0..31
        int col = (tid & 7) * 8;         // 0..56
        float4 v0 = *(const float4*)&W[(size_t)(c0 + r) * 64 + col];
        float4 v1 = *(const float4*)&W[(size_t)(c0 + r) * 64 + col + 4];
        tile[r][col]     = v0.x; tile[r][col + 1] = v0.y;
        tile[r][col + 2] = v0.z; tile[r][col + 3] = v0.w;
        tile[r][col + 4] = v1.x; tile[r][col + 5] = v1.y;
        tile[r][col + 6] = v1.z; tile[r][col + 7] = v1.w;
    }
    __syncthreads();
    int j   = tid >> 2;                  // 0..63
    int sub = tid & 3;                   // 0..3
    int cc  = sub * 8;
    ushort tmp[8];
#pragma unroll
    for (int e = 0; e < 8; e++) tmp[e] = f2bits(tile[cc + e][j]);
    int kc = c0 >> 5;
    ushort* dst = &WtF[((size_t)kc * 192 + m * 64 + j) * 32 + sub * 8];
    *(uint4*)(dst) = *(uint4*)&tmp[0];
}

// ---------------- Kernel 1: QKV GEMM v3 (R16, unchanged) -----------------
__launch_bounds__(256, 3)
__global__ void qkv_kernel(const float* __restrict__ x, const ushort* __restrict__ WtF,
                           ushort* __restrict__ qws, ushort* __restrict__ kws,
                           ushort* __restrict__ vws) {
    __shared__ float  xsA[4][32 * 32];   // 4 x 4 KB
    __shared__ ushort xsB[3][6144];      // 3 x 12 KB

    int tid  = threadIdx.x;
    int wid  = tid >> 6;
    int lane = tid & 63;
    int l15  = lane & 15;
    int hi4  = lane >> 4;
    int row0 = blockIdx.x * 32;

    int rA  = tid >> 3;
    int gcA = (tid & 7) ^ (rA & 7);
    const float* gpA = x + (size_t)(row0 + rA) * CC + gcA * 4;

    int PB0 = tid, PB1 = tid + 256, PB2 = tid + 512;
    int LB0 = PB0 ^ ((PB0 >> 3) & 3);
    int LB1 = PB1 ^ ((PB1 >> 3) & 3);
    int LB2 = PB2 ^ ((PB2 >> 3) & 3);

    int PrB[3];
#pragma unroll
    for (int nt = 0; nt < 3; nt++) {
        int Lr = (wid * 48 + nt * 16 + l15) * 4 + hi4;
        PrB[nt] = Lr ^ ((Lr >> 3) & 3);
    }

    f32x4 acc[2][3];
#pragma unroll
    for (int mm = 0; mm < 2; mm++)
#pragma unroll
        for (int nt = 0; nt < 3; nt++) acc[mm][nt] = (f32x4){0.f, 0.f, 0.f, 0.f};

    auto stageA = [&](int t) {
        GLL16(gpA + t * 32, &xsA[t & 3][(size_t)tid * 4]);
    };
    auto stageB = [&](int t) {
        int buf = t % 3;
        const ushort* bsrc = WtF + (size_t)t * 6144;
        GLL16(bsrc + LB0 * 8, &xsB[buf][PB0 * 8]);
        GLL16(bsrc + LB1 * 8, &xsB[buf][PB1 * 8]);
        GLL16(bsrc + LB2 * 8, &xsB[buf][PB2 * 8]);
    };

    stageA(0); stageA(1);
    stageB(0); stageB(1);
    stageA(2); stageA(3);

#pragma unroll
    for (int p = 0; p < 12; p++) {
        if (p < 11) asm volatile("s_waitcnt vmcnt(2)" ::: "memory");
        else        asm volatile("s_waitcnt vmcnt(0)" ::: "memory");
        __builtin_amdgcn_s_barrier();
        __builtin_amdgcn_sched_barrier(0);

#pragma unroll
        for (int u = 0; u < 2; u++) {
            int t    = 2 * p + u;
            int bufA = t & 3;
            int bufB = t % 3;
            bf16x8 af[2];
#pragma unroll
            for (int mm = 0; mm < 2; mm++) {
                int row = mm * 16 + l15;
                const float* base = &xsA[bufA][row * 32];
                float4 fa = *(const float4*)(base + (((2 * hi4)     ^ (row & 7)) * 4));
                float4 fb = *(const float4*)(base + (((2 * hi4 + 1) ^ (row & 7)) * 4));
                uint32_t w0 = cvtpk(fa.x, fa.y), w1 = cvtpk(fa.z, fa.w);
                uint32_t w2 = cvtpk(fb.x, fb.y), w3 = cvtpk(fb.z, fb.w);
                uint4 u4 = {w0, w1, w2, w3};
                af[mm] = __builtin_bit_cast(bf16x8, u4);
            }
#pragma unroll
            for (int nt = 0; nt < 3; nt++) {
                bf16x8 b = __builtin_bit_cast(bf16x8, *(const uint4*)&xsB[bufB][PrB[nt] * 8]);
                acc[0][nt] = __builtin_amdgcn_mfma_f32_16x16x32_bf16(af[0], b, acc[0][nt], 0, 0, 0);
                acc[1][nt] = __builtin_amdgcn_mfma_f32_16x16x32_bf16(af[1], b, acc[1][nt], 0, 0, 0);
            }
        }
        __builtin_amdgcn_s_barrier();
        if (p < 11) { stageB(2 * p + 2); stageB(2 * p + 3); }
        if (p < 10) { stageA(2 * p + 4); stageA(2 * p + 5); }
    }

    const float qscale = 0.125f * 1.4426950408889634f;   // exp2 domain
    int bidx = row0 >> 11;
#pragma unroll
    for (int mm = 0; mm < 2; mm++) {
        int r0 = row0 + mm * 16 + 4 * hi4;
        int t0 = r0 & 2047;
#pragma unroll
        for (int nt = 0; nt < 3; nt++) {
            int c = wid * 48 + nt * 16 + l15;
            int m = c >> 6;
            int j = c & 63;
            if (m == 0) {
#pragma unroll
                for (int r = 0; r < 4; r++)
                    qws[(size_t)(r0 + r) * 64 + j] = f2bits(acc[mm][nt][r] * qscale);
            } else if (m == 1) {
#pragma unroll
                for (int r = 0; r < 4; r++)
                    kws[(size_t)(r0 + r) * 64 + j] = f2bits(acc[mm][nt][r]);
            } else {
                ushort4 pk;
                pk.x = f2bits(acc[mm][nt][0]);
                pk.y = f2bits(acc[mm][nt][1]);
                pk.z = f2bits(acc[mm][nt][2]);
                pk.w = f2bits(acc[mm][nt][3]);
                *(ushort4*)&vws[((size_t)bidx * 64 + j) * TT + t0] = pk;
            }
        }
    }
}

// ---------------- Kernel 2: flash, XCD-aligned batches (R16, unchanged) --
__launch_bounds__(256, 3)
__global__ void flash_kernel(const ushort* __restrict__ qg, const ushort* __restrict__ kg,
                             const ushort* __restrict__ vtg, float* __restrict__ out,
                             ushort* __restrict__ pO, float* __restrict__ pM,
                             float* __restrict__ pL) {
    __shared__ ushort Ks[3][64 * 64];
    __shared__ ushort Vs[3][64 * 64];

    int tid  = threadIdx.x;
    int wid  = tid >> 6;
    int lane = tid & 63;
    int l31  = lane & 31;
    int hi   = lane >> 5;

    int b  = blockIdx.x & 7;            // XCD-aligned batch
    int tp = blockIdx.x >> 3;
    int g  = 0;
    while (tp >= ((g + 2) * (g + 2)) >> 2) g++;
    int seg   = tp - (((g + 1) * (g + 1)) >> 2);
    int nseg  = (g + 2) >> 1;
    int Qb    = g * 128;
    int Q0w   = Qb + wid * 32;
    int s_beg = seg * 256;
    int s_end = (s_beg + 256 < Qb + 128) ? s_beg + 256 : Qb + 128;
    int nt    = (s_end - s_beg) >> 6;

    int rS  = tid >> 3;
    int gcS = (tid & 7) ^ (rS & 7);
    const ushort* kS = kg  + ((size_t)b * TT + rS) * 64 + gcS * 8;
    const ushort* vS = vtg + ((size_t)b * 64 + rS) * TT + gcS * 8;

    auto stage = [&](int tt) {
        int buf = tt % 3;
        int ss  = s_beg + tt * 64;
        const ushort* kA = kS + (size_t)ss * 64;
        const ushort* vA = vS + ss;
        GLL16(kA,            &Ks[buf][tid * 8]);
        GLL16(kA + 32 * 64,  &Ks[buf][(tid + 256) * 8]);
        GLL16(vA,            &Vs[buf][tid * 8]);
        GLL16(vA + 32 * TT,  &Vs[buf][(tid + 256) * 8]);
    };

    const ushort* qp = qg + ((size_t)b * TT + Q0w + l31) * 64 + hi * 8;
    bf16x8 qf[4];
#pragma unroll
    for (int c = 0; c < 4; c++)
        qf[c] = __builtin_bit_cast(bf16x8, *(const uint4*)(qp + c * 16));

    f32x16 o0 = (f32x16)(0.f), o1 = (f32x16)(0.f);
    float m  = -INFINITY;
    float lp = 0.f;

    stage(0);
    if (nt > 1) stage(1);

    for (int t = 0; t < nt; t++) {
        if (t < nt - 1) asm volatile("s_waitcnt vmcnt(4)" ::: "memory");
        else            asm volatile("s_waitcnt vmcnt(0)" ::: "memory");
        __builtin_amdgcn_s_barrier();
        __builtin_amdgcn_sched_barrier(0);
        if (t + 2 < nt) stage(t + 2);

        int s0 = s_beg + t * 64;
        if (s0 < Q0w + 32) {
            int buf = t % 3;
            bf16x8 kf[2][4];
#pragma unroll
            for (int tt = 0; tt < 2; tt++) {
                int rk = tt * 32 + l31;
                const ushort* base = &Ks[buf][rk * 64];
                int sw = rk & 7;
#pragma unroll
                for (int c = 0; c < 4; c++)
                    kf[tt][c] = __builtin_bit_cast(bf16x8,
                        *(const uint4*)(base + (((c * 2 + hi) ^ sw) * 8)));
            }

            f32x16 st0 = (f32x16)(0.f), st1 = (f32x16)(0.f);
            __builtin_amdgcn_s_setprio(1);
#pragma unroll
            for (int c = 0; c < 4; c++)
                st0 = __builtin_amdgcn_mfma_f32_32x32x16_bf16(kf[0][c], qf[c], st0, 0, 0, 0);
#pragma unroll
            for (int c = 0; c < 4; c++)
                st1 = __builtin_amdgcn_mfma_f32_32x32x16_bf16(kf[1][c], qf[c], st1, 0, 0, 0);
            __builtin_amdgcn_s_setprio(0);

            if (s0 + 63 > Q0w) {
                int th0 = Q0w + l31 - s0 - 4 * hi;
                int th1 = th0 - 32;
#pragma unroll
                for (int r = 0; r < 16; r++) {
                    int kvl = (r & 3) + 8 * (r >> 2);
                    if (kvl > th0) st0[r] = -INFINITY;
                    if (kvl > th1) st1[r] = -INFINITY;
                }
            }

            float a[16];
#pragma unroll
            for (int r = 0; r < 16; r++) a[r] = fmaxf(st0[r], st1[r]);
#pragma unroll
            for (int off = 8; off > 0; off >>= 1)
#pragma unroll
                for (int i = 0; i < 8; i++)
                    if (i < off) a[i] = fmaxf(a[i], a[i + off]);
            float pmax = fmaxf(a[0], __shfl_xor(a[0], 32));
            if (__any(pmax > m + 11.54f)) {
                float mn = fmaxf(m, pmax);
                float al = exp2f(m - mn);
                lp *= al;
#pragma unroll
                for (int r = 0; r < 16; r++) { o0[r] *= al; o1[r] *= al; }
                m = mn;
            }
#pragma unroll
            for (int r = 0; r < 16; r++) {
                st0[r] = exp2f(st0[r] - m);
                st1[r] = exp2f(st1[r] - m);
            }
            float s[16];
#pragma unroll
            for (int r = 0; r < 16; r++) s[r] = st0[r] + st1[r];
#pragma unroll
            for (int off = 8; off > 0; off >>= 1)
#pragma unroll
                for (int i = 0; i < 8; i++)
                    if (i < off) s[i] += s[i + off];
            lp += s[0];

            bf16x8 pf[4];
            {
                uint32_t w0, w1, w2, w3;
                w0 = cvtpk(st0[0], st0[1]);  w1 = cvtpk(st0[2], st0[3]);
                w2 = cvtpk(st0[4], st0[5]);  w3 = cvtpk(st0[6], st0[7]);
                pswap(w0, w2); pswap(w1, w3);
                uint4 u0 = {w0, w1, w2, w3}; pf[0] = __builtin_bit_cast(bf16x8, u0);
                w0 = cvtpk(st0[8], st0[9]);  w1 = cvtpk(st0[10], st0[11]);
                w2 = cvtpk(st0[12], st0[13]); w3 = cvtpk(st0[14], st0[15]);
                pswap(w0, w2); pswap(w1, w3);
                uint4 u1 = {w0, w1, w2, w3}; pf[1] = __builtin_bit_cast(bf16x8, u1);
                w0 = cvtpk(st1[0], st1[1]);  w1 = cvtpk(st1[2], st1[3]);
                w2 = cvtpk(st1[4], st1[5]);  w3 = cvtpk(st1[6], st1[7]);
                pswap(w0, w2); pswap(w1, w3);
                uint4 u2 = {w0, w1, w2, w3}; pf[2] = __builtin_bit_cast(bf16x8, u2);
                w0 = cvtpk(st1[8], st1[9]);  w1 = cvtpk(st1[10], st1[11]);
                w2 = cvtpk(st1[12], st1[13]); w3 = cvtpk(st1[14], st1[15]);
                pswap(w0, w2); pswap(w1, w3);
                uint4 u3 = {w0, w1, w2, w3}; pf[3] = __builtin_bit_cast(bf16x8, u3);
            }

            bf16x8 vf[2][4];
#pragma unroll
            for (int ht = 0; ht < 2; ht++) {
                int rv = ht * 32 + l31;
                const ushort* base = &Vs[buf][rv * 64];
                int sw = rv & 7;
#pragma unroll
                for (int c = 0; c < 4; c++)
                    vf[ht][c] = __builtin_bit_cast(bf16x8,
                        *(const uint4*)(base + (((c * 2 + hi) ^ sw) * 8)));
            }

            __builtin_amdgcn_s_setprio(1);
#pragma unroll
            for (int c = 0; c < 4; c++)
                o0 = __builtin_amdgcn_mfma_f32_32x32x16_bf16(vf[0][c], pf[c], o0, 0, 0, 0);
#pragma unroll
            for (int c = 0; c < 4; c++)
                o1 = __builtin_amdgcn_mfma_f32_32x32x16_bf16(vf[1][c], pf[c], o1, 0, 0, 0);
            __builtin_amdgcn_s_setprio(0);
        }
    }

    float lsum = lp + __shfl_xor(lp, 32);

    if (nseg == 1) {
        float inv = 1.f / lsum;
        float* ob = out + ((size_t)b * TT + Q0w + l31) * 64;
#pragma unroll
        for (int gg = 0; gg < 4; gg++) {
            float4 v0 = {o0[4*gg] * inv, o0[4*gg+1] * inv, o0[4*gg+2] * inv, o0[4*gg+3] * inv};
            *(float4*)(ob + 8 * gg + 4 * hi) = v0;
            float4 v1 = {o1[4*gg] * inv, o1[4*gg+1] * inv, o1[4*gg+2] * inv, o1[4*gg+3] * inv};
            *(float4*)(ob + 32 + 8 * gg + 4 * hi) = v1;
        }
    } else {
        int tb = b * NTPB + tp;
        ushort* pb = pO + (size_t)tb * 8192 + (size_t)(wid * 32 + l31) * 64;
#pragma unroll
        for (int gg = 0; gg < 4; gg++) {
            ushort4 v0 = {f2bits(o0[4*gg]), f2bits(o0[4*gg+1]),
                          f2bits(o0[4*gg+2]), f2bits(o0[4*gg+3])};
            *(ushort4*)(pb + 8 * gg + 4 * hi) = v0;
            ushort4 v1 = {f2bits(o1[4*gg]), f2bits(o1[4*gg+1]),
                          f2bits(o1[4*gg+2]), f2bits(o1[4*gg+3])};
            *(ushort4*)(pb + 32 + 8 * gg + 4 * hi) = v1;
        }
        if (hi == 0) {
            pM[(size_t)tb * 128 + wid * 32 + l31] = m;
            pL[(size_t)tb * 128 + wid * 32 + l31] = lsum;
        }
    }
}

// ---------------- Kernel 3: merge bf16 partials, 4 blocks per (b,g) ------
// Block = (b, g, quarter). 32 rows x 64 cols per block; thread = (row,
// 8-col group): nseg uint4 loads. Grid = 8*14*4 = 448.
__launch_bounds__(256)
__global__ void merge_kernel(const ushort* __restrict__ pO, const float* __restrict__ pM,
                             const float* __restrict__ pL, float* __restrict__ out) {
    int b    = blockIdx.x / 56;
    int rem  = blockIdx.x % 56;
    int g    = 2 + (rem >> 2);
    int q4   = rem & 3;
    int nseg = (g + 2) >> 1;
    int tbase = b * NTPB + (((g + 1) * (g + 1)) >> 2);

    int row  = q4 * 32 + (threadIdx.x >> 3);   // 0..127
    int colg = (threadIdx.x & 7) * 8;          // 0..56

    float mstar = -INFINITY;
    for (int s = 0; s < nseg; s++)
        mstar = fmaxf(mstar, pM[(size_t)(tbase + s) * 128 + row]);

    float oa[8] = {0.f, 0.f, 0.f, 0.f, 0.f, 0.f, 0.f, 0.f};
    float la = 0.f;
    for (int s = 0; s < nseg; s++) {
        float w = exp2f(pM[(size_t)(tbase + s) * 128 + row] - mstar);
        la += w * pL[(size_t)(tbase + s) * 128 + row];
        uint4 u = *(const uint4*)&pO[(size_t)(tbase + s) * 8192 + (size_t)row * 64 + colg];
#pragma unroll
        for (int e = 0; e < 4; e++) {
            uint32_t wdw = ((const uint32_t*)&u)[e];
            oa[e*2]     += w * bits2f((ushort)(wdw & 0xffff));
            oa[e*2 + 1] += w * bits2f((ushort)(wdw >> 16));
        }
    }
    float inv = 1.f / la;
    float* ob = out + ((size_t)b * TT + g * 128 + row) * 64 + colg;
    float4 r0 = {oa[0] * inv, oa[1] * inv, oa[2] * inv, oa[3] * inv};
    float4 r1 = {oa[4] * inv, oa[5] * inv, oa[6] * inv, oa[7] * inv};
    *(float4*)(ob)     = r0;
    *(float4*)(ob + 4) = r1;
}

// ---------------- launch --------------------------------------------------
extern "C" void kernel_launch(void* const* d_in, const int* in_sizes, int n_in,
                              void* d_out, int out_size, void* d_ws, size_t ws_size,
                              hipStream_t stream) {
    const float* x  = (const float*)d_in[0];
    const float* Wk = (const float*)d_in[1];
    const float* Wq = (const float*)d_in[2];
    const float* Wv = (const float*)d_in[3];
    float* out = (float*)d_out;

    char* ws = (char*)d_ws;
    ushort* WtF = (ushort*)(ws);                 // 288 KB (fragment-major)
    ushort* qws = (ushort*)(ws + 0x50000);       // 2 MB
    ushort* kws = (ushort*)(ws + 0x250000);      // 2 MB
    ushort* vws = (ushort*)(ws + 0x450000);      // 2 MB  [b][h][t]
    ushort* pO  = (ushort*)(ws + 0x650000);      // 9.4 MB (bf16 partials)
    float*  pM  = (float*)(ws + 0x1050000);      // 288 KB
    float*  pL  = (float*)(ws + 0x1098000);      // 288 KB

    wt_kernel<<<72, 256, 0, stream>>>(Wk, Wq, Wv, WtF);
    qkv_kernel<<<(BB * TT) / 32, 256, 0, stream>>>(x, WtF, qws, kws, vws);
    flash_kernel<<<BB * NTPB, 256, 0, stream>>>(qws, kws, vws, out, pO, pM, pL);
    merge_kernel<<<BB * 14 * 4, 256, 0, stream>>>(pO, pM, pL, out);
}